// Round 11
// baseline (46.323 us; speedup 1.0000x reference)
//
#include <hip/hip_runtime.h>
#include <hip/hip_bf16.h>
#include <math.h>

#define NB 256
#define NL 256
#define NH 128
#define NK 8

typedef __attribute__((ext_vector_type(8))) short bf16x8;
typedef __attribute__((ext_vector_type(4))) short s16x4;
typedef __attribute__((ext_vector_type(4))) float f32x4;

static __device__ __forceinline__ short f2bf(float x) {
    __hip_bfloat16 b = __float2bfloat16(x);
    return *reinterpret_cast<short*>(&b);
}
static __device__ __forceinline__ float bf2f(short s) {
    union { unsigned int u; float f; } v;
    v.u = ((unsigned int)(unsigned short)s) << 16;
    return v.f;
}

#define MFMA __builtin_amdgcn_mfma_f32_16x16x32_bf16

// ---------------------------------------------------------------------------
// Setup: split W into bf16 hi/lo + transposed copies (global, L2/L3-hot).
// ---------------------------------------------------------------------------
__global__ __launch_bounds__(256) void setup_w_kernel(const float* __restrict__ W,
                                                      short* __restrict__ whi,
                                                      short* __restrict__ wlo,
                                                      short* __restrict__ wthi,
                                                      short* __restrict__ wtlo) {
    const int id = blockIdx.x * 256 + threadIdx.x;   // h*128 + j
    const int h = id >> 7, j = id & 127;
    const float w = W[id];
    const short hi = f2bf(w);
    const short lo = f2bf(w - bf2f(hi));
    whi[id] = hi;
    wlo[id] = lo;
    wthi[j * 128 + h] = hi;
    wtlo[j * 128 + h] = lo;
}

// ---------------------------------------------------------------------------
// Fused per-batch kernel: 256 blocks x 1024 threads (16 waves).
// Deferred-normalization routing: P1 raw exp -> P2 m_raw -> P3 cap (+1/ksum,
// +norm partials) -> P5 g (x squash-scale) -> P6 logits (MFMA C-carry).
// W fragments register-resident. ~15 barriers total.
// ---------------------------------------------------------------------------
__global__ __launch_bounds__(1024) void fused_kernel(const float* __restrict__ e,
                                                     const float* __restrict__ b_init,
                                                     const short* __restrict__ whi,
                                                     const short* __restrict__ wlo,
                                                     const short* __restrict__ wthi,
                                                     const short* __restrict__ wtlo,
                                                     float* __restrict__ out) {
    const int b = blockIdx.x;
    const int t = threadIdx.x;
    const int lane = t & 63, wv = t >> 6;
    const int l16 = lane & 15, grp = lane >> 4;

    __shared__ __align__(16) short eThi[128 * 264]; // 67584 B  e^T hi
    __shared__ __align__(16) short eTlo[128 * 264]; // 67584 B  e^T lo
    __shared__ __align__(16) short cax[16 * 264];   // 8448 B   raw exp rows 0-7 hi, 8-15 lo
    __shared__ __align__(16) short mpk[16 * 136];   // 4352 B   m_raw hi/lo
    __shared__ __align__(16) short cappk[16 * 136]; // 4352 B   raw cap (ksum-scaled) hi/lo
    __shared__ __align__(16) short gpk[16 * 136];   // 4352 B   g / mu hi/lo
    __shared__ float enl[256];                      // 1024 B
    __shared__ float red32[128];                    // 512 B    exp partial sums / sv partials
    __shared__ __align__(16) float nrmp[64];        // 256 B    cap norm partials
    __shared__ float ksf[8], svals[8], strv[8], Ps[28];

    const float* ebg = e + (size_t)b * (NL * NH);

    // ---- W fragments -> registers (used by waves 0-7 in P3/P5) ----
    bf16x8 wh3[4], wl3[4], wh5[4], wl5[4];
    if (wv < 8) {
#pragma unroll
        for (int ks = 0; ks < 4; ++ks) {
            const int bo = (wv * 16 + l16) * 128 + ks * 32 + grp * 8;
            wh3[ks] = *(const bf16x8*)&whi[bo];
            wl3[ks] = *(const bf16x8*)&wlo[bo];
            wh5[ks] = *(const bf16x8*)&wthi[bo];
            wl5[ks] = *(const bf16x8*)&wtlo[bo];
        }
    }

    // ---- per-lane e row-fragments (P6/P9 A-operand) + row norms ----
    bf16x8 eah[4], eal[4];
    {
        const int row = wv * 16 + l16;
        float ss = 0.f;
#pragma unroll
        for (int ks = 0; ks < 4; ++ks) {
            const float4 f0 = *(const float4*)&ebg[row * 128 + ks * 32 + grp * 8];
            const float4 f1 = *(const float4*)&ebg[row * 128 + ks * 32 + grp * 8 + 4];
            const float fx[8] = {f0.x, f0.y, f0.z, f0.w, f1.x, f1.y, f1.z, f1.w};
            bf16x8 hv, lv;
#pragma unroll
            for (int j = 0; j < 8; ++j) {
                const short h = f2bf(fx[j]);
                hv[j] = h;
                lv[j] = f2bf(fx[j] - bf2f(h));
                ss += fx[j] * fx[j];
            }
            eah[ks] = hv;
            eal[ks] = lv;
        }
        ss += __shfl_xor(ss, 16);
        ss += __shfl_xor(ss, 32);
        if (grp == 0) enl[row] = sqrtf(ss) + 1e-8f;
    }

    // ---- stage e^T (bf16 hi/lo): coalesced column-gather ----
#pragma unroll
    for (int i = 0; i < 4; ++i) {
        const int p = i * 1024 + t;
        const int h = p & 127, c = p >> 7;
        float le[8];
#pragma unroll
        for (int j = 0; j < 8; ++j) le[j] = ebg[(c * 8 + j) * 128 + h];
        bf16x8 hv, lv;
#pragma unroll
        for (int j = 0; j < 8; ++j) {
            const short s = f2bf(le[j]);
            hv[j] = s;
            lv[j] = f2bf(le[j] - bf2f(s));
        }
        *(bf16x8*)&eThi[h * 264 + c * 8] = hv;
        *(bf16x8*)&eTlo[h * 264 + c * 8] = lv;
    }

    // ---- logits in registers: lane l16<8 = capsule k, l = wv*16+grp*4+r ----
    float lr0 = 0.f, lr1 = 0.f, lr2 = 0.f, lr3 = 0.f;
    if (l16 < 8) {
        const float4 bi = *(const float4*)&b_init[(size_t)b * 2048 + l16 * 256 + wv * 16 + grp * 4];
        lr0 = bi.x; lr1 = bi.y; lr2 = bi.z; lr3 = bi.w;
    }
    __syncthreads();   // B0

    for (int iter = 0; iter < 3; ++iter) {
        // ===== P1: raw exp (no normalization, no max-sub; f32-safe) =====
        {
            const float e0 = expf(lr0), e1 = expf(lr1);
            const float e2 = expf(lr2), e3 = expf(lr3);
            float s4 = e0 + e1 + e2 + e3;
            s4 += __shfl_xor(s4, 16);
            s4 += __shfl_xor(s4, 32);
            if (l16 < 8 && grp == 0) red32[wv * 8 + l16] = s4;
            if (l16 < 8) {
                const int lb = wv * 16 + grp * 4;
                const float cv[4] = {e0, e1, e2, e3};
                s16x4 his, los;
#pragma unroll
                for (int j = 0; j < 4; ++j) {
                    const short h = f2bf(cv[j]);
                    his[j] = h;
                    los[j] = f2bf(cv[j] - bf2f(h));
                }
                *(s16x4*)&cax[l16 * 264 + lb] = his;
                *(s16x4*)&cax[(l16 + 8) * 264 + lb] = los;
            }
        }
        __syncthreads();   // B1

        // ===== P2: m_raw = exp @ e  (A=[exp_hi;exp_lo], B=eT hi/lo) =====
        if (wv < 8) {
            const int n0 = wv * 16;
            f32x4 acc = (f32x4){0.f, 0.f, 0.f, 0.f};
#pragma unroll
            for (int ks = 0; ks < 8; ++ks) {
                const bf16x8 af = *(const bf16x8*)&cax[l16 * 264 + ks * 32 + grp * 8];
                const bf16x8 bh = *(const bf16x8*)&eThi[(n0 + l16) * 264 + ks * 32 + grp * 8];
                const bf16x8 bl = *(const bf16x8*)&eTlo[(n0 + l16) * 264 + ks * 32 + grp * 8];
                acc = MFMA(af, bh, acc, 0, 0, 0);
                acc = MFMA(af, bl, acc, 0, 0, 0);
            }
            f32x4 ms;
#pragma unroll
            for (int r = 0; r < 4; ++r) ms[r] = acc[r] + __shfl_xor(acc[r], 32);
            if (grp < 2) {
#pragma unroll
                for (int r = 0; r < 4; ++r) {
                    const int k = grp * 4 + r, h = n0 + l16;
                    const short hv = f2bf(ms[r]);
                    mpk[k * 136 + h] = hv;
                    mpk[(k + 8) * 136 + h] = f2bf(ms[r] - bf2f(hv));
                }
            }
        }
        __syncthreads();   // B2

        // ===== P3: cap = (m_raw @ W^T) * (1/ksum)  + norm partials =====
        if (wv < 8) {
            float inv = 0.f;
            if (l16 < 8) {
                float kss = 0.f;
#pragma unroll
                for (int w = 0; w < 16; ++w) kss += red32[w * 8 + l16];
                inv = 1.0f / kss;
            }
            const int n0 = wv * 16;
            f32x4 acc = (f32x4){0.f, 0.f, 0.f, 0.f};
#pragma unroll
            for (int ks = 0; ks < 4; ++ks) {
                const bf16x8 af = *(const bf16x8*)&mpk[l16 * 136 + ks * 32 + grp * 8];
                acc = MFMA(af, wh3[ks], acc, 0, 0, 0);
                acc = MFMA(af, wl3[ks], acc, 0, 0, 0);
            }
            f32x4 cs;
            float pn[4];
#pragma unroll
            for (int r = 0; r < 4; ++r) {
                cs[r] = acc[r] + __shfl_xor(acc[r], 32);
                cs[r] *= __shfl(inv, grp * 4 + r);
                float p2 = cs[r] * cs[r];
                p2 += __shfl_xor(p2, 1);
                p2 += __shfl_xor(p2, 2);
                p2 += __shfl_xor(p2, 4);
                p2 += __shfl_xor(p2, 8);
                pn[r] = p2;
            }
            if (l16 == 0 && grp < 2) {
                float4 pv;
                pv.x = pn[0]; pv.y = pn[1]; pv.z = pn[2]; pv.w = pn[3];
                *(float4*)&nrmp[wv * 8 + grp * 4] = pv;
            }
            if (iter < 2 && grp < 2) {
#pragma unroll
                for (int r = 0; r < 4; ++r) {
                    const int k = grp * 4 + r, h = n0 + l16;
                    const short hv = f2bf(cs[r]);
                    cappk[k * 136 + h] = hv;
                    cappk[(k + 8) * 136 + h] = f2bf(cs[r] - bf2f(hv));
                }
            }
            if (iter == 2 && wv == 0 && grp == 0 && l16 < 8) ksf[l16] = inv;
        }
        __syncthreads();   // B3

        if (iter < 2) {
            // ===== P5: g = (cap @ W) * squash_scale(k) =====
            if (wv < 8) {
                float sc = 0.f;
                if (l16 < 8) {
                    float n = 0.f;
#pragma unroll
                    for (int w = 0; w < 8; ++w) n += nrmp[w * 8 + l16];
                    sc = n / (1.0f + n) / sqrtf(n + 1e-9f);
                }
                const int n0 = wv * 16;
                f32x4 acc = (f32x4){0.f, 0.f, 0.f, 0.f};
#pragma unroll
                for (int ks = 0; ks < 4; ++ks) {
                    const bf16x8 af = *(const bf16x8*)&cappk[l16 * 136 + ks * 32 + grp * 8];
                    acc = MFMA(af, wh5[ks], acc, 0, 0, 0);
                    acc = MFMA(af, wl5[ks], acc, 0, 0, 0);
                }
                f32x4 gs;
#pragma unroll
                for (int r = 0; r < 4; ++r) {
                    gs[r] = acc[r] + __shfl_xor(acc[r], 32);
                    gs[r] *= __shfl(sc, grp * 4 + r);
                }
                if (grp < 2) {
#pragma unroll
                    for (int r = 0; r < 4; ++r) {
                        const int k = grp * 4 + r, h = n0 + l16;
                        const short hv = f2bf(gs[r]);
                        gpk[k * 136 + h] = hv;
                        gpk[(k + 8) * 136 + h] = f2bf(gs[r] - bf2f(hv));
                    }
                }
            }
            __syncthreads();   // B4

            // ===== P6: logits += e . g  (A=e regs, B=[g_hi|g_lo], C=logits) =====
            {
                f32x4 acc;
                acc[0] = (l16 < 8) ? lr0 : 0.f;
                acc[1] = (l16 < 8) ? lr1 : 0.f;
                acc[2] = (l16 < 8) ? lr2 : 0.f;
                acc[3] = (l16 < 8) ? lr3 : 0.f;
#pragma unroll
                for (int ks = 0; ks < 4; ++ks) {
                    const bf16x8 bf = *(const bf16x8*)&gpk[l16 * 136 + ks * 32 + grp * 8];
                    acc = MFMA(eah[ks], bf, acc, 0, 0, 0);
                    acc = MFMA(eal[ks], bf, acc, 0, 0, 0);
                }
                lr0 = acc[0] + __shfl_xor(acc[0], 8);
                lr1 = acc[1] + __shfl_xor(acc[1], 8);
                lr2 = acc[2] + __shfl_xor(acc[2], 8);
                lr3 = acc[3] + __shfl_xor(acc[3], 8);
            }
            // no trailing barrier (next iter's P1 touches disjoint state)
        }
    }

    // ===== strength (wave 8) ∥ mu_n -> gpk (waves 0-7) =====
    if (wv == 8 && lane < 8) {
        float n = 0.f;
#pragma unroll
        for (int w = 0; w < 8; ++w) n += nrmp[w * 8 + lane];
        strv[lane] = n / (1.0f + n) * sqrtf(n) / sqrtf(n + 1e-9f);
    }
    if (wv < 8) {
        const int k = wv;
        float x0 = bf2f(mpk[k * 136 + lane]) + bf2f(mpk[(k + 8) * 136 + lane]);
        float x1 = bf2f(mpk[k * 136 + 64 + lane]) + bf2f(mpk[(k + 8) * 136 + 64 + lane]);
        float s = x0 * x0 + x1 * x1;
#pragma unroll
        for (int o = 32; o; o >>= 1) s += __shfl_xor(s, o);
        const float nv = sqrtf(s) + 1e-8f;   // scale-invariant: m_raw/||m_raw||
        x0 /= nv; x1 /= nv;
        short hv = f2bf(x0);
        gpk[k * 136 + lane] = hv;
        gpk[(k + 8) * 136 + lane] = f2bf(x0 - bf2f(hv));
        hv = f2bf(x1);
        gpk[k * 136 + 64 + lane] = hv;
        gpk[(k + 8) * 136 + 64 + lane] = f2bf(x1 - bf2f(hv));
    }
    __syncthreads();   // B5

    // ===== P9: dot = e . mu (MFMA), weight by c/enl ∥ Gram pairs =====
    {
        f32x4 acc = (f32x4){0.f, 0.f, 0.f, 0.f};
#pragma unroll
        for (int ks = 0; ks < 4; ++ks) {
            const bf16x8 bf = *(const bf16x8*)&gpk[l16 * 136 + ks * 32 + grp * 8];
            acc = MFMA(eah[ks], bf, acc, 0, 0, 0);
            acc = MFMA(eal[ks], bf, acc, 0, 0, 0);
        }
        f32x4 d;
#pragma unroll
        for (int r = 0; r < 4; ++r) d[r] = acc[r] + __shfl_xor(acc[r], 8);
        float sv = 0.f;
        if (l16 < 8) {
            const float kinv = ksf[l16];
#pragma unroll
            for (int r = 0; r < 4; ++r) {
                const int l = wv * 16 + grp * 4 + r;
                const float cv = (bf2f(cax[l16 * 264 + l]) + bf2f(cax[(l16 + 8) * 264 + l])) * kinv;
                sv += d[r] * cv / enl[l];
            }
        }
        sv += __shfl_xor(sv, 16);
        sv += __shfl_xor(sv, 32);
        if (l16 < 8 && grp == 0) red32[wv * 8 + l16] = sv;
    }
#pragma unroll
    for (int pp = 0; pp < 2; ++pp) {
        const int p = wv + pp * 16;
        if (p < 28) {
            int i = 0, rem = p;
            while (rem >= 7 - i) { rem -= 7 - i; ++i; }
            const int j = i + 1 + rem;
            const float mi0 = bf2f(gpk[i * 136 + lane]) + bf2f(gpk[(i + 8) * 136 + lane]);
            const float mi1 = bf2f(gpk[i * 136 + 64 + lane]) + bf2f(gpk[(i + 8) * 136 + 64 + lane]);
            const float mj0 = bf2f(gpk[j * 136 + lane]) + bf2f(gpk[(j + 8) * 136 + lane]);
            const float mj1 = bf2f(gpk[j * 136 + 64 + lane]) + bf2f(gpk[(j + 8) * 136 + 64 + lane]);
            float v = mi0 * mj0 + mi1 * mj1;
#pragma unroll
            for (int o = 32; o; o >>= 1) v += __shfl_xor(v, o);
            if (lane == 0) Ps[p] = v;
        }
    }
    __syncthreads();   // B6
    if (t < 8) {
        float s = 0.f;
#pragma unroll
        for (int w = 0; w < 16; ++w) s += red32[w * 8 + t];
        svals[t] = s;
    }
    __syncthreads();   // B7

    // ===== serial scoring =====
    if (t == 0) {
        int idx[8];
        for (int i = 0; i < 8; ++i) idx[i] = i;
        for (int a = 1; a < 8; ++a) {
            const int key = idx[a];
            const float kv = strv[key];
            int bb = a - 1;
            while (bb >= 0 && strv[idx[bb]] < kv) { idx[bb + 1] = idx[bb]; --bb; }
            idx[bb + 1] = key;
        }
        float best = -1e30f;
        int bestk = 2;
        float cons_sum = 0.f, pair_sum = 0.f;
        for (int kk = 1; kk <= 8; ++kk) {
            const int ni = idx[kk - 1];
            cons_sum += svals[ni];
            for (int a = 0; a < kk - 1; ++a) {
                const int ia = idx[a];
                const int lo = ia < ni ? ia : ni;
                const int hi2 = ia < ni ? ni : ia;
                const int off0 = lo * 7 - lo * (lo - 1) / 2;
                pair_sum += Ps[off0 + hi2 - lo - 1];
            }
            if (kk >= 2) {
                const float cons = cons_sum / (kk * 256.0f);
                const float divv = 1.0f - (2.0f / (kk * (kk - 1))) * pair_sum;
                const float score = 0.5f * cons + 0.5f * divv;
                out[256 + b * 7 + (kk - 2)] = score;
                if (score > best) { best = score; bestk = kk; }
            }
        }
        out[b] = (float)bestk;
    }
}

// ---------------------------------------------------------------------------
extern "C" void kernel_launch(void* const* d_in, const int* in_sizes, int n_in,
                              void* d_out, int out_size, void* d_ws, size_t ws_size,
                              hipStream_t stream) {
    const float* e = (const float*)d_in[0];
    const float* W = (const float*)d_in[1];
    const float* b_init = (const float*)d_in[2];
    float* out = (float*)d_out;

    short* whi = (short*)d_ws;
    short* wlo = whi + 16384;
    short* wthi = wlo + 16384;
    short* wtlo = wthi + 16384;

    hipLaunchKernelGGL(setup_w_kernel, dim3(64), dim3(256), 0, stream, W, whi, wlo, wthi, wtlo);
    hipLaunchKernelGGL(fused_kernel, dim3(NB), dim3(1024), 0, stream,
                       e, b_init, whi, wlo, wthi, wtlo, out);
}

// Round 12
// 39.045 us; speedup vs baseline: 1.1864x; 1.1864x over previous
//
#include <hip/hip_runtime.h>
#include <hip/hip_bf16.h>
#include <math.h>

#define NB 256
#define NL 256
#define NH 128
#define NK 8

typedef __attribute__((ext_vector_type(8))) short bf16x8;
typedef __attribute__((ext_vector_type(4))) short s16x4;
typedef __attribute__((ext_vector_type(4))) float f32x4;

static __device__ __forceinline__ short f2bf(float x) {
    __hip_bfloat16 b = __float2bfloat16(x);
    return *reinterpret_cast<short*>(&b);
}
static __device__ __forceinline__ float bf2f(short s) {
    union { unsigned int u; float f; } v;
    v.u = ((unsigned int)(unsigned short)s) << 16;
    return v.f;
}

#define MFMA __builtin_amdgcn_mfma_f32_16x16x32_bf16

// ---------------------------------------------------------------------------
// Setup: split W into bf16 hi/lo + transposed copies (global, L2/L3-hot).
// ---------------------------------------------------------------------------
__global__ __launch_bounds__(256) void setup_w_kernel(const float* __restrict__ W,
                                                      short* __restrict__ whi,
                                                      short* __restrict__ wlo,
                                                      short* __restrict__ wthi,
                                                      short* __restrict__ wtlo) {
    const int id = blockIdx.x * 256 + threadIdx.x;   // h*128 + j
    const int h = id >> 7, j = id & 127;
    const float w = W[id];
    const short hi = f2bf(w);
    const short lo = f2bf(w - bf2f(hi));
    whi[id] = hi;
    wlo[id] = lo;
    wthi[j * 128 + h] = hi;
    wtlo[j * 128 + h] = lo;
}

// ---------------------------------------------------------------------------
// Fused per-batch kernel: 256 blocks x 1024 threads (16 waves).
// Deferred-normalization routing (round-11 structure), W frags from global
// (L2-hot; register preload spilled at 1024 threads -> reverted).
// ---------------------------------------------------------------------------
__global__ __launch_bounds__(1024) void fused_kernel(const float* __restrict__ e,
                                                     const float* __restrict__ b_init,
                                                     const short* __restrict__ whi,
                                                     const short* __restrict__ wlo,
                                                     const short* __restrict__ wthi,
                                                     const short* __restrict__ wtlo,
                                                     float* __restrict__ out) {
    const int b = blockIdx.x;
    const int t = threadIdx.x;
    const int lane = t & 63, wv = t >> 6;
    const int l16 = lane & 15, grp = lane >> 4;

    __shared__ __align__(16) short eThi[128 * 264]; // 67584 B  e^T hi
    __shared__ __align__(16) short eTlo[128 * 264]; // 67584 B  e^T lo
    __shared__ __align__(16) short cax[16 * 264];   // 8448 B   raw exp rows 0-7 hi, 8-15 lo
    __shared__ __align__(16) short mpk[16 * 136];   // 4352 B   m_raw hi/lo
    __shared__ __align__(16) short cappk[16 * 136]; // 4352 B   cap (ksum-scaled) hi/lo
    __shared__ __align__(16) short gpk[16 * 136];   // 4352 B   g / mu hi/lo
    __shared__ float enl[256];                      // 1024 B
    __shared__ float red32[128];                    // 512 B
    __shared__ __align__(16) float nrmp[64];        // 256 B
    __shared__ float ksf[8], svals[8], strv[8], Ps[28];

    const float* ebg = e + (size_t)b * (NL * NH);

    // ---- per-lane e row-fragments (P6/P9 A-operand) + row norms ----
    bf16x8 eah[4], eal[4];
    {
        const int row = wv * 16 + l16;
        float ss = 0.f;
#pragma unroll
        for (int ks = 0; ks < 4; ++ks) {
            const float4 f0 = *(const float4*)&ebg[row * 128 + ks * 32 + grp * 8];
            const float4 f1 = *(const float4*)&ebg[row * 128 + ks * 32 + grp * 8 + 4];
            const float fx[8] = {f0.x, f0.y, f0.z, f0.w, f1.x, f1.y, f1.z, f1.w};
            bf16x8 hv, lv;
#pragma unroll
            for (int j = 0; j < 8; ++j) {
                const short h = f2bf(fx[j]);
                hv[j] = h;
                lv[j] = f2bf(fx[j] - bf2f(h));
                ss += fx[j] * fx[j];
            }
            eah[ks] = hv;
            eal[ks] = lv;
        }
        ss += __shfl_xor(ss, 16);
        ss += __shfl_xor(ss, 32);
        if (grp == 0) enl[row] = sqrtf(ss) + 1e-8f;
    }

    // ---- stage e^T (bf16 hi/lo): coalesced column-gather ----
#pragma unroll
    for (int i = 0; i < 4; ++i) {
        const int p = i * 1024 + t;
        const int h = p & 127, c = p >> 7;
        float le[8];
#pragma unroll
        for (int j = 0; j < 8; ++j) le[j] = ebg[(c * 8 + j) * 128 + h];
        bf16x8 hv, lv;
#pragma unroll
        for (int j = 0; j < 8; ++j) {
            const short s = f2bf(le[j]);
            hv[j] = s;
            lv[j] = f2bf(le[j] - bf2f(s));
        }
        *(bf16x8*)&eThi[h * 264 + c * 8] = hv;
        *(bf16x8*)&eTlo[h * 264 + c * 8] = lv;
    }

    // ---- logits in registers: lane l16<8 = capsule k, l = wv*16+grp*4+r ----
    float lr0 = 0.f, lr1 = 0.f, lr2 = 0.f, lr3 = 0.f;
    if (l16 < 8) {
        const float4 bi = *(const float4*)&b_init[(size_t)b * 2048 + l16 * 256 + wv * 16 + grp * 4];
        lr0 = bi.x; lr1 = bi.y; lr2 = bi.z; lr3 = bi.w;
    }
    __syncthreads();   // B0

    for (int iter = 0; iter < 3; ++iter) {
        // ===== P1: raw exp (no normalization, no max-sub; f32-safe) =====
        {
            const float e0 = expf(lr0), e1 = expf(lr1);
            const float e2 = expf(lr2), e3 = expf(lr3);
            float s4 = e0 + e1 + e2 + e3;
            s4 += __shfl_xor(s4, 16);
            s4 += __shfl_xor(s4, 32);
            if (l16 < 8 && grp == 0) red32[wv * 8 + l16] = s4;
            if (l16 < 8) {
                const int lb = wv * 16 + grp * 4;
                const float cv[4] = {e0, e1, e2, e3};
                s16x4 his, los;
#pragma unroll
                for (int j = 0; j < 4; ++j) {
                    const short h = f2bf(cv[j]);
                    his[j] = h;
                    los[j] = f2bf(cv[j] - bf2f(h));
                }
                *(s16x4*)&cax[l16 * 264 + lb] = his;
                *(s16x4*)&cax[(l16 + 8) * 264 + lb] = los;
            }
        }
        __syncthreads();   // B1

        // ===== P2: m_raw = exp @ e  (A=[exp_hi;exp_lo], B=eT hi/lo) =====
        if (wv < 8) {
            const int n0 = wv * 16;
            f32x4 acc = (f32x4){0.f, 0.f, 0.f, 0.f};
#pragma unroll
            for (int ks = 0; ks < 8; ++ks) {
                const bf16x8 af = *(const bf16x8*)&cax[l16 * 264 + ks * 32 + grp * 8];
                const bf16x8 bh = *(const bf16x8*)&eThi[(n0 + l16) * 264 + ks * 32 + grp * 8];
                const bf16x8 bl = *(const bf16x8*)&eTlo[(n0 + l16) * 264 + ks * 32 + grp * 8];
                acc = MFMA(af, bh, acc, 0, 0, 0);
                acc = MFMA(af, bl, acc, 0, 0, 0);
            }
            f32x4 ms;
#pragma unroll
            for (int r = 0; r < 4; ++r) ms[r] = acc[r] + __shfl_xor(acc[r], 32);
            if (grp < 2) {
#pragma unroll
                for (int r = 0; r < 4; ++r) {
                    const int k = grp * 4 + r, h = n0 + l16;
                    const short hv = f2bf(ms[r]);
                    mpk[k * 136 + h] = hv;
                    mpk[(k + 8) * 136 + h] = f2bf(ms[r] - bf2f(hv));
                }
            }
        }
        __syncthreads();   // B2

        // ===== P3: cap = (m_raw @ W^T) * (1/ksum)  + norm partials =====
        if (wv < 8) {
            float inv = 0.f;
            if (l16 < 8) {
                float kss = 0.f;
#pragma unroll
                for (int w = 0; w < 16; ++w) kss += red32[w * 8 + l16];
                inv = 1.0f / kss;
            }
            const int n0 = wv * 16;
            f32x4 acc = (f32x4){0.f, 0.f, 0.f, 0.f};
#pragma unroll
            for (int ks = 0; ks < 4; ++ks) {
                const bf16x8 af = *(const bf16x8*)&mpk[l16 * 136 + ks * 32 + grp * 8];
                const int bo = (n0 + l16) * 128 + ks * 32 + grp * 8;
                acc = MFMA(af, *(const bf16x8*)&whi[bo], acc, 0, 0, 0);
                acc = MFMA(af, *(const bf16x8*)&wlo[bo], acc, 0, 0, 0);
            }
            f32x4 cs;
            float pn[4];
#pragma unroll
            for (int r = 0; r < 4; ++r) {
                cs[r] = acc[r] + __shfl_xor(acc[r], 32);
                cs[r] *= __shfl(inv, grp * 4 + r);
                float p2 = cs[r] * cs[r];
                p2 += __shfl_xor(p2, 1);
                p2 += __shfl_xor(p2, 2);
                p2 += __shfl_xor(p2, 4);
                p2 += __shfl_xor(p2, 8);
                pn[r] = p2;
            }
            if (l16 == 0 && grp < 2) {
                float4 pv;
                pv.x = pn[0]; pv.y = pn[1]; pv.z = pn[2]; pv.w = pn[3];
                *(float4*)&nrmp[wv * 8 + grp * 4] = pv;
            }
            if (iter < 2 && grp < 2) {
#pragma unroll
                for (int r = 0; r < 4; ++r) {
                    const int k = grp * 4 + r, h = n0 + l16;
                    const short hv = f2bf(cs[r]);
                    cappk[k * 136 + h] = hv;
                    cappk[(k + 8) * 136 + h] = f2bf(cs[r] - bf2f(hv));
                }
            }
            if (iter == 2 && wv == 0 && grp == 0 && l16 < 8) ksf[l16] = inv;
        }
        __syncthreads();   // B3

        if (iter < 2) {
            // ===== P5: g = (cap @ W) * squash_scale(k) =====
            if (wv < 8) {
                float sc = 0.f;
                if (l16 < 8) {
                    float n = 0.f;
#pragma unroll
                    for (int w = 0; w < 8; ++w) n += nrmp[w * 8 + l16];
                    sc = n / (1.0f + n) / sqrtf(n + 1e-9f);
                }
                const int n0 = wv * 16;
                f32x4 acc = (f32x4){0.f, 0.f, 0.f, 0.f};
#pragma unroll
                for (int ks = 0; ks < 4; ++ks) {
                    const bf16x8 af = *(const bf16x8*)&cappk[l16 * 136 + ks * 32 + grp * 8];
                    const int bo = (n0 + l16) * 128 + ks * 32 + grp * 8;
                    acc = MFMA(af, *(const bf16x8*)&wthi[bo], acc, 0, 0, 0);
                    acc = MFMA(af, *(const bf16x8*)&wtlo[bo], acc, 0, 0, 0);
                }
                f32x4 gs;
#pragma unroll
                for (int r = 0; r < 4; ++r) {
                    gs[r] = acc[r] + __shfl_xor(acc[r], 32);
                    gs[r] *= __shfl(sc, grp * 4 + r);
                }
                if (grp < 2) {
#pragma unroll
                    for (int r = 0; r < 4; ++r) {
                        const int k = grp * 4 + r, h = n0 + l16;
                        const short hv = f2bf(gs[r]);
                        gpk[k * 136 + h] = hv;
                        gpk[(k + 8) * 136 + h] = f2bf(gs[r] - bf2f(hv));
                    }
                }
            }
            __syncthreads();   // B4

            // ===== P6: logits += e . g  (A=e regs, B=[g_hi|g_lo], C=logits) =====
            {
                f32x4 acc;
                acc[0] = (l16 < 8) ? lr0 : 0.f;
                acc[1] = (l16 < 8) ? lr1 : 0.f;
                acc[2] = (l16 < 8) ? lr2 : 0.f;
                acc[3] = (l16 < 8) ? lr3 : 0.f;
#pragma unroll
                for (int ks = 0; ks < 4; ++ks) {
                    const bf16x8 bf = *(const bf16x8*)&gpk[l16 * 136 + ks * 32 + grp * 8];
                    acc = MFMA(eah[ks], bf, acc, 0, 0, 0);
                    acc = MFMA(eal[ks], bf, acc, 0, 0, 0);
                }
                lr0 = acc[0] + __shfl_xor(acc[0], 8);
                lr1 = acc[1] + __shfl_xor(acc[1], 8);
                lr2 = acc[2] + __shfl_xor(acc[2], 8);
                lr3 = acc[3] + __shfl_xor(acc[3], 8);
            }
            // no trailing barrier (next iter's P1 touches disjoint state)
        }
    }

    // ===== strength (wave 8) ∥ mu_n -> gpk (waves 0-7) =====
    if (wv == 8 && lane < 8) {
        float n = 0.f;
#pragma unroll
        for (int w = 0; w < 8; ++w) n += nrmp[w * 8 + lane];
        strv[lane] = n / (1.0f + n) * sqrtf(n) / sqrtf(n + 1e-9f);
    }
    if (wv < 8) {
        const int k = wv;
        float x0 = bf2f(mpk[k * 136 + lane]) + bf2f(mpk[(k + 8) * 136 + lane]);
        float x1 = bf2f(mpk[k * 136 + 64 + lane]) + bf2f(mpk[(k + 8) * 136 + 64 + lane]);
        float s = x0 * x0 + x1 * x1;
#pragma unroll
        for (int o = 32; o; o >>= 1) s += __shfl_xor(s, o);
        const float nv = sqrtf(s) + 1e-8f;   // scale-invariant: m_raw/||m_raw||
        x0 /= nv; x1 /= nv;
        short hv = f2bf(x0);
        gpk[k * 136 + lane] = hv;
        gpk[(k + 8) * 136 + lane] = f2bf(x0 - bf2f(hv));
        hv = f2bf(x1);
        gpk[k * 136 + 64 + lane] = hv;
        gpk[(k + 8) * 136 + 64 + lane] = f2bf(x1 - bf2f(hv));
    }
    __syncthreads();   // B5

    // ===== P9: dot = e . mu (MFMA), weight by c/enl ∥ Gram pairs =====
    {
        f32x4 acc = (f32x4){0.f, 0.f, 0.f, 0.f};
#pragma unroll
        for (int ks = 0; ks < 4; ++ks) {
            const bf16x8 bf = *(const bf16x8*)&gpk[l16 * 136 + ks * 32 + grp * 8];
            acc = MFMA(eah[ks], bf, acc, 0, 0, 0);
            acc = MFMA(eal[ks], bf, acc, 0, 0, 0);
        }
        f32x4 d;
#pragma unroll
        for (int r = 0; r < 4; ++r) d[r] = acc[r] + __shfl_xor(acc[r], 8);
        float sv = 0.f;
        if (l16 < 8) {
            const float kinv = ksf[l16];
#pragma unroll
            for (int r = 0; r < 4; ++r) {
                const int l = wv * 16 + grp * 4 + r;
                const float cv = (bf2f(cax[l16 * 264 + l]) + bf2f(cax[(l16 + 8) * 264 + l])) * kinv;
                sv += d[r] * cv / enl[l];
            }
        }
        sv += __shfl_xor(sv, 16);
        sv += __shfl_xor(sv, 32);
        if (l16 < 8 && grp == 0) red32[wv * 8 + l16] = sv;
    }
#pragma unroll
    for (int pp = 0; pp < 2; ++pp) {
        const int p = wv + pp * 16;
        if (p < 28) {
            int i = 0, rem = p;
            while (rem >= 7 - i) { rem -= 7 - i; ++i; }
            const int j = i + 1 + rem;
            const float mi0 = bf2f(gpk[i * 136 + lane]) + bf2f(gpk[(i + 8) * 136 + lane]);
            const float mi1 = bf2f(gpk[i * 136 + 64 + lane]) + bf2f(gpk[(i + 8) * 136 + 64 + lane]);
            const float mj0 = bf2f(gpk[j * 136 + lane]) + bf2f(gpk[(j + 8) * 136 + lane]);
            const float mj1 = bf2f(gpk[j * 136 + 64 + lane]) + bf2f(gpk[(j + 8) * 136 + 64 + lane]);
            float v = mi0 * mj0 + mi1 * mj1;
#pragma unroll
            for (int o = 32; o; o >>= 1) v += __shfl_xor(v, o);
            if (lane == 0) Ps[p] = v;
        }
    }
    __syncthreads();   // B6
    if (t < 8) {
        float s = 0.f;
#pragma unroll
        for (int w = 0; w < 16; ++w) s += red32[w * 8 + t];
        svals[t] = s;
    }
    __syncthreads();   // B7

    // ===== serial scoring =====
    if (t == 0) {
        int idx[8];
        for (int i = 0; i < 8; ++i) idx[i] = i;
        for (int a = 1; a < 8; ++a) {
            const int key = idx[a];
            const float kv = strv[key];
            int bb = a - 1;
            while (bb >= 0 && strv[idx[bb]] < kv) { idx[bb + 1] = idx[bb]; --bb; }
            idx[bb + 1] = key;
        }
        float best = -1e30f;
        int bestk = 2;
        float cons_sum = 0.f, pair_sum = 0.f;
        for (int kk = 1; kk <= 8; ++kk) {
            const int ni = idx[kk - 1];
            cons_sum += svals[ni];
            for (int a = 0; a < kk - 1; ++a) {
                const int ia = idx[a];
                const int lo = ia < ni ? ia : ni;
                const int hi2 = ia < ni ? ni : ia;
                const int off0 = lo * 7 - lo * (lo - 1) / 2;
                pair_sum += Ps[off0 + hi2 - lo - 1];
            }
            if (kk >= 2) {
                const float cons = cons_sum / (kk * 256.0f);
                const float divv = 1.0f - (2.0f / (kk * (kk - 1))) * pair_sum;
                const float score = 0.5f * cons + 0.5f * divv;
                out[256 + b * 7 + (kk - 2)] = score;
                if (score > best) { best = score; bestk = kk; }
            }
        }
        out[b] = (float)bestk;
    }
}

// ---------------------------------------------------------------------------
extern "C" void kernel_launch(void* const* d_in, const int* in_sizes, int n_in,
                              void* d_out, int out_size, void* d_ws, size_t ws_size,
                              hipStream_t stream) {
    const float* e = (const float*)d_in[0];
    const float* W = (const float*)d_in[1];
    const float* b_init = (const float*)d_in[2];
    float* out = (float*)d_out;

    short* whi = (short*)d_ws;
    short* wlo = whi + 16384;
    short* wthi = wlo + 16384;
    short* wtlo = wthi + 16384;

    hipLaunchKernelGGL(setup_w_kernel, dim3(64), dim3(256), 0, stream, W, whi, wlo, wthi, wtlo);
    hipLaunchKernelGGL(fused_kernel, dim3(NB), dim3(1024), 0, stream,
                       e, b_init, whi, wlo, wthi, wtlo, out);
}